// Round 4
// baseline (2672.932 us; speedup 1.0000x reference)
//
#include <hip/hip_runtime.h>
#include <cmath>

#define BB 8
#define DD 1024
#define NP 4096
#define KC 32
#define HH 512
#define PP 128
#define BN_EPS 1e-5f

typedef unsigned short u16;
typedef short s16x8 __attribute__((ext_vector_type(8)));
typedef float f32x4 __attribute__((ext_vector_type(4)));

// ---------------- wave helpers ----------------
__device__ __forceinline__ float waveReduceSum(float v) {
#pragma unroll
  for (int o = 32; o > 0; o >>= 1) v += __shfl_down(v, o, 64);
  return v;
}
__device__ __forceinline__ float waveAllMax(float v) {
#pragma unroll
  for (int o = 32; o > 0; o >>= 1) v = fmaxf(v, __shfl_xor(v, o, 64));
  return v;
}
__device__ __forceinline__ float waveAllSum(float v) {
#pragma unroll
  for (int o = 32; o > 0; o >>= 1) v += __shfl_xor(v, o, 64);
  return v;
}

// ---------------- bf16 3-way split: y = h + m + l + O(2^-24 |y|) ----------
__device__ __forceinline__ void split3(float y, short& h, short& m, short& l) {
  unsigned uy = __float_as_uint(y);
  h = (short)(uy >> 16);
  float r1 = y - __uint_as_float(uy & 0xFFFF0000u);
  unsigned um = __float_as_uint(r1);
  m = (short)(um >> 16);
  float r2 = r1 - __uint_as_float(um & 0xFFFF0000u);
  l = (short)(__float_as_uint(r2) >> 16);
}

// ---------------- W pre-permute + 3-split: block (mt,kc): [q][m][j] = W[mt*BM+m][kc*32+q*8+j]
template<int BM>
__global__ __launch_bounds__(256) void convW3(
    const float* __restrict__ W, u16* __restrict__ hb, u16* __restrict__ mb, u16* __restrict__ lb,
    int K) {
  int mt = blockIdx.x, kc = blockIdx.y, KCH = gridDim.y;
  const int AU = BM * 4;
  for (int u = threadIdx.x; u < AU; u += 256) {
    int q = u / BM, m = u % BM;
    const float* wp = W + (size_t)(mt * BM + m) * K + kc * 32 + q * 8;
    s16x8 hv, mv, lv;
#pragma unroll
    for (int j = 0; j < 8; j++) {
      short h, mm, l; split3(wp[j], h, mm, l);
      hv[j] = h; mv[j] = mm; lv[j] = l;
    }
    size_t ob = ((size_t)(mt * KCH + kc)) * (size_t)(BM * 32) + (size_t)u * 8;
    *(s16x8*)(hb + ob) = hv;
    *(s16x8*)(mb + ob) = mv;
    *(s16x8*)(lb + ob) = lv;
  }
}

// ---------------- bf16x3 MFMA GEMM (f32-equivalent): Y[b,m,n] = sum_k W[m,k]*f(X[b,k,n]) + bias[m]
// X is f32 [b][K][4096]; f = identity or relu(fma(x,sc,sh)); Y f32 [b][M][4096]
template<int BM, int MBLK, int MT, int NT, int WM, bool BNRELU>
__global__ __launch_bounds__(256) void gemm_mfma3(
    const u16* __restrict__ wh, const u16* __restrict__ wmid, const u16* __restrict__ wl,
    const float* __restrict__ bias, const float* __restrict__ X,
    const float* __restrict__ bnsc, const float* __restrict__ bnsh,
    float* __restrict__ Y, int K, int M) {
  __shared__ s16x8 AhS[BM * 4], AmS[BM * 4], AlS[BM * 4];
  __shared__ s16x8 BhS[512], BmS[512], BlS[512];
  const int KCH = K / 32;
  const int tid = threadIdx.x;
  const int bz = blockIdx.z;
  int bid = blockIdx.x;
  int xs = bid & 7, rr = bid >> 3;
  int m_idx = rr % MBLK;
  int n_idx = xs + 8 * (rr / MBLK);

  const int w = tid >> 6, l = tid & 63, q = l >> 4, col = l & 15;
  const int wm = (WM == 1) ? 0 : (w >> 1);
  const int wn = (WM == 1) ? w : (w & 1);

  f32x4 acc[MT][NT];
#pragma unroll
  for (int i = 0; i < MT; i++)
#pragma unroll
    for (int j = 0; j < NT; j++) { acc[i][j][0] = 0.f; acc[i][j][1] = 0.f; acc[i][j][2] = 0.f; acc[i][j][3] = 0.f; }

  const short* Ah = (const short*)AhS;
  const short* Am = (const short*)AmS;
  const short* Al = (const short*)AlS;
  const short* Bh = (const short*)BhS;
  const short* Bm = (const short*)BmS;
  const short* Bl = (const short*)BlS;

  for (int kc = 0; kc < KCH; kc++) {
    // stage A (pre-permuted weights)
    {
      size_t ab = ((size_t)(m_idx * KCH + kc)) * (size_t)(BM * 32);
      const s16x8* awh = (const s16x8*)(wh + ab);
      const s16x8* awm = (const s16x8*)(wmid + ab);
      const s16x8* awl = (const s16x8*)(wl + ab);
      for (int u = tid; u < BM * 4; u += 256) { AhS[u] = awh[u]; AmS[u] = awm[u]; AlS[u] = awl[u]; }
    }
    // stage B from f32 (optional BN+ReLU), split3
    for (int u = tid; u < 512; u += 256) {
      int qq = u >> 7, n = u & 127;
      const float* fp = X + (size_t)bz * K * NP + (size_t)(kc * 32 + qq * 8) * NP + (size_t)n_idx * 128 + n;
      s16x8 hv, mv, lv;
#pragma unroll
      for (int j = 0; j < 8; j++) {
        float y = fp[(size_t)j * NP];
        if (BNRELU) y = fmaxf(fmaf(y, bnsc[kc * 32 + qq * 8 + j], bnsh[kc * 32 + qq * 8 + j]), 0.f);
        short h, mm, ll; split3(y, h, mm, ll);
        hv[j] = h; mv[j] = mm; lv[j] = ll;
      }
      BhS[u] = hv; BmS[u] = mv; BlS[u] = lv;
    }
    __syncthreads();
    // compute: 6 MFMAs per tile for f32-grade product
    s16x8 ah[MT], am[MT], al[MT];
#pragma unroll
    for (int i = 0; i < MT; i++) {
      int off = (q * BM + wm * (MT * 16) + i * 16 + col) * 8;
      ah[i] = *(const s16x8*)(Ah + off);
      am[i] = *(const s16x8*)(Am + off);
      al[i] = *(const s16x8*)(Al + off);
    }
#pragma unroll
    for (int j = 0; j < NT; j++) {
      int offb = (q * 128 + wn * (NT * 16) + j * 16 + col) * 8;
      s16x8 bh = *(const s16x8*)(Bh + offb);
      s16x8 bm = *(const s16x8*)(Bm + offb);
      s16x8 bl = *(const s16x8*)(Bl + offb);
#pragma unroll
      for (int i = 0; i < MT; i++) {
        acc[i][j] = __builtin_amdgcn_mfma_f32_16x16x32_bf16(ah[i], bh, acc[i][j], 0, 0, 0);
        acc[i][j] = __builtin_amdgcn_mfma_f32_16x16x32_bf16(ah[i], bm, acc[i][j], 0, 0, 0);
        acc[i][j] = __builtin_amdgcn_mfma_f32_16x16x32_bf16(am[i], bh, acc[i][j], 0, 0, 0);
        acc[i][j] = __builtin_amdgcn_mfma_f32_16x16x32_bf16(ah[i], bl, acc[i][j], 0, 0, 0);
        acc[i][j] = __builtin_amdgcn_mfma_f32_16x16x32_bf16(am[i], bm, acc[i][j], 0, 0, 0);
        acc[i][j] = __builtin_amdgcn_mfma_f32_16x16x32_bf16(al[i], bh, acc[i][j], 0, 0, 0);
      }
    }
    __syncthreads();
  }
  // epilogue: f32 row-major
#pragma unroll
  for (int i = 0; i < MT; i++) {
#pragma unroll
    for (int r = 0; r < 4; r++) {
      int m = m_idx * BM + wm * (MT * 16) + i * 16 + q * 4 + r;
      float bv = bias[m];
#pragma unroll
      for (int j = 0; j < NT; j++) {
        int n = n_idx * 128 + wn * (NT * 16) + j * 16 + col;
        Y[((size_t)bz * M + m) * 4096 + n] = acc[i][j][r] + bv;
      }
    }
  }
}

// ---------------- BN (training, batch stats over B and N) per channel
__global__ __launch_bounds__(256) void bnstats(
    const float* __restrict__ Y, const float* __restrict__ g, const float* __restrict__ beta,
    float* __restrict__ scale, float* __restrict__ shift, int C, int N) {
  int c = blockIdx.x;
  float s = 0.f, sq = 0.f;
  for (int b = 0; b < BB; b++) {
    const float* p = Y + ((size_t)b * C + c) * N;
    for (int n = threadIdx.x; n < N; n += 256) { float v = p[n]; s += v; sq += v * v; }
  }
  __shared__ float shs[4], shq[4];
  int lane = threadIdx.x & 63, wid = threadIdx.x >> 6;
  s = waveReduceSum(s); sq = waveReduceSum(sq);
  if (lane == 0) { shs[wid] = s; shq[wid] = sq; }
  __syncthreads();
  if (threadIdx.x == 0) {
    float S = shs[0] + shs[1] + shs[2] + shs[3];
    float Q = shq[0] + shq[1] + shq[2] + shq[3];
    float cnt = (float)(BB * N);
    float mean = S / cnt;
    float var = Q / cnt - mean * mean;
    float sc = g[c] / sqrtf(var + BN_EPS);
    scale[c] = sc; shift[c] = beta[c] - mean * sc;
  }
}

// ---------------- softmax over K (axis=1), write score, lse per (b,n), pi partial sums
__global__ __launch_bounds__(256) void softmax_pi(
    const float* __restrict__ LSm, float* __restrict__ score,
    float* __restrict__ lseArr, float* __restrict__ pi_raw) {
  int gidx = blockIdx.x * 256 + threadIdx.x;
  int b = gidx / NP, n = gidx % NP;
  const float* p = LSm + (size_t)b * KC * NP + n;
  float v[KC];
  float m = -1e30f;
#pragma unroll
  for (int k = 0; k < KC; k++) { v[k] = p[(size_t)k * NP]; m = fmaxf(m, v[k]); }
  float s = 0.f;
#pragma unroll
  for (int k = 0; k < KC; k++) { v[k] = expf(v[k] - m); s += v[k]; }
  float inv = 1.f / s;
  float* qq = score + (size_t)b * KC * NP + n;
#pragma unroll
  for (int k = 0; k < KC; k++) { v[k] *= inv; qq[(size_t)k * NP] = v[k]; }
  lseArr[gidx] = m + logf(s);
  __shared__ float ps[KC];
  if (threadIdx.x < KC) ps[threadIdx.x] = 0.f;
  __syncthreads();
  int lane = threadIdx.x & 63;
#pragma unroll
  for (int k = 0; k < KC; k++) {
    float w = waveReduceSum(v[k]);
    if (lane == 0) atomicAdd(&ps[k], w);
  }
  __syncthreads();
  if (threadIdx.x < KC) atomicAdd(&pi_raw[b * KC + threadIdx.x], ps[threadIdx.x]);
}

// ---------------- vlad accumulation (split over n, atomic)
__global__ __launch_bounds__(256) void vlad_accum(
    const float* __restrict__ feat, const float* __restrict__ score, float* __restrict__ vlad) {
  const int SPLIT_LEN = NP / 8;
  int sp = blockIdx.x, dt = blockIdx.y, b = blockIdx.z;
  int d0 = dt * 128;
  int n_start = sp * SPLIT_LEN;
  __shared__ float As[32][132];
  __shared__ float Bs[32][36];
  int tid = threadIdx.x;
  int tx = tid % 16;
  int ty = tid / 16;
  float acc[8][2] = {};
  const float* fb = feat + (size_t)b * DD * NP;
  const float* sb = score + (size_t)b * KC * NP;
  for (int nc = 0; nc < SPLIT_LEN; nc += 32) {
    int n0 = n_start + nc;
    for (int i = tid; i < 128 * 32; i += 256) {
      int r = i >> 5, c = i & 31;
      As[c][r] = fb[(size_t)(d0 + r) * NP + n0 + c];
    }
    for (int i = tid; i < 32 * 32; i += 256) {
      int r = i >> 5, c = i & 31;
      Bs[c][r] = sb[(size_t)r * NP + n0 + c];
    }
    __syncthreads();
#pragma unroll 4
    for (int kk = 0; kk < 32; kk++) {
      float ra[8], rb[2];
#pragma unroll
      for (int i = 0; i < 8; i++) ra[i] = As[kk][ty * 8 + i];
      rb[0] = Bs[kk][tx * 2]; rb[1] = Bs[kk][tx * 2 + 1];
#pragma unroll
      for (int i = 0; i < 8; i++) { acc[i][0] = fmaf(ra[i], rb[0], acc[i][0]); acc[i][1] = fmaf(ra[i], rb[1], acc[i][1]); }
    }
    __syncthreads();
  }
#pragma unroll
  for (int i = 0; i < 8; i++)
#pragma unroll
    for (int j = 0; j < 2; j++)
      atomicAdd(&vlad[((size_t)b * DD + d0 + ty * 8 + i) * KC + tx * 2 + j], acc[i][j]);
}

__global__ __launch_bounds__(256) void vlad_fin(
    float* __restrict__ vlad, const float* __restrict__ pi_raw, float* __restrict__ gmax) {
  int idx = blockIdx.x * 256 + threadIdx.x;
  int b = idx / DD;
  float* p = vlad + (size_t)idx * KC;
  const float* pr = pi_raw + b * KC;
  float gm = -1e30f;
#pragma unroll
  for (int k = 0; k < KC; k++) {
    float v = p[k] / fmaxf(pr[k], 1e-4f);
    p[k] = v;
    gm = fmaxf(gm, v);
  }
  gmax[idx] = gm;
}

__global__ __launch_bounds__(256) void nmu_norm_k(
    const float* __restrict__ vlad, float* __restrict__ nmun) {
  int b = blockIdx.x, tid = threadIdx.x;
  int k = tid & 31, dg = tid >> 5;
  float s = 0.f;
  for (int d = dg * 128; d < dg * 128 + 128; d++) {
    float v = vlad[((size_t)b * DD + d) * KC + k]; s += v * v;
  }
  __shared__ float sh[8][32];
  sh[dg][k] = s;
  __syncthreads();
  if (tid < 32) {
    float t = 0.f;
    for (int i = 0; i < 8; i++) t += sh[i][tid];
    nmun[b * KC + tid] = fmaxf(sqrtf(t), 1e-12f);
  }
}

__global__ __launch_bounds__(256) void nf_norm_k(
    const float* __restrict__ feat, float* __restrict__ nfn) {
  int idx = blockIdx.x * 256 + threadIdx.x;
  int b = idx / NP, n = idx % NP;
  const float* p = feat + (size_t)b * DD * NP + n;
  float s = 0.f;
  for (int d = 0; d < DD; d++) { float v = p[(size_t)d * NP]; s += v * v; }
  nfn[idx] = fmaxf(sqrtf(s), 1e-12f);
}

// ---------------- cost dot accumulation (split over d, atomic)
__global__ __launch_bounds__(256) void cost_accum(
    const float* __restrict__ feat, const float* __restrict__ vlad, float* __restrict__ costd) {
  int sp = blockIdx.x, nt = blockIdx.y, b = blockIdx.z;
  int n0 = nt * 128;
  int d_start = sp * (DD / 4);
  __shared__ float As[32][132];
  __shared__ float Bs[32][36];
  int tid = threadIdx.x;
  int tx = tid % 16;
  int ty = tid / 16;
  float acc[8][2] = {};
  const float* fb = feat + (size_t)b * DD * NP;
  const float* vb = vlad + (size_t)b * DD * KC;
  for (int dc = 0; dc < DD / 4; dc += 32) {
    int dd0 = d_start + dc;
    for (int i = tid; i < 32 * 128; i += 256) {
      int r = i >> 7, c = i & 127;
      As[r][c] = fb[(size_t)(dd0 + r) * NP + n0 + c];
    }
    for (int i = tid; i < 32 * 32; i += 256) {
      int r = i >> 5, c = i & 31;
      Bs[r][c] = vb[(size_t)(dd0 + r) * KC + c];
    }
    __syncthreads();
#pragma unroll 4
    for (int kk = 0; kk < 32; kk++) {
      float ra[8], rb[2];
#pragma unroll
      for (int i = 0; i < 8; i++) ra[i] = As[kk][ty * 8 + i];
      rb[0] = Bs[kk][tx * 2]; rb[1] = Bs[kk][tx * 2 + 1];
#pragma unroll
      for (int i = 0; i < 8; i++) { acc[i][0] = fmaf(ra[i], rb[0], acc[i][0]); acc[i][1] = fmaf(ra[i], rb[1], acc[i][1]); }
    }
    __syncthreads();
  }
#pragma unroll
  for (int i = 0; i < 8; i++)
#pragma unroll
    for (int j = 0; j < 2; j++)
      atomicAdd(&costd[((size_t)b * NP + n0 + ty * 8 + i) * KC + tx * 2 + j], acc[i][j]);
}

__global__ __launch_bounds__(256) void cost_fin(
    float* __restrict__ costd, const float* __restrict__ nfn, const float* __restrict__ nmun) {
  size_t idx = (size_t)blockIdx.x * 256 + threadIdx.x;
  int k = (int)(idx & 31);
  size_t nn = idx >> 5;
  int n = (int)(nn % NP);
  int b = (int)(nn / NP);
  float dot = costd[idx];
  costd[idx] = 2.f - 2.f * dot / (nfn[b * NP + n] * nmun[b * KC + k]);
}

// ---------------- fused sinkhorn (25 iters) + loss: one block of 1024 per batch
__global__ __launch_bounds__(1024) void sinkhorn_loss(
    const float* __restrict__ cost, const float* __restrict__ LSm,
    const float* __restrict__ lseArr, float* __restrict__ out0,
    float logp, float logq) {
  const float EPS = 1e-3f, IEPS = 1000.f;
  int b = blockIdx.x;
  int tid = threadIdx.x;
  int lane = tid & 63, wid = tid >> 6;
  const float* cb = cost + (size_t)b * NP * KC;
  __shared__ float vsh[KC];
  __shared__ float wred[KC][17];
  __shared__ float bmf[KC];
  if (tid < KC) vsh[tid] = 0.f;
  __syncthreads();
  float u[4];
  for (int t = 0; t < 25; t++) {
    float lm[KC];
#pragma unroll
    for (int k = 0; k < KC; k++) lm[k] = -3.0e38f;
#pragma unroll 1
    for (int r = 0; r < 4; r++) {
      const float* crow = cb + (size_t)(r * 1024 + tid) * KC;
      float c[KC];
#pragma unroll
      for (int k8 = 0; k8 < 8; k8++) {
        f32x4 t4 = *(const f32x4*)(crow + k8 * 4);
        c[k8 * 4 + 0] = t4[0]; c[k8 * 4 + 1] = t4[1]; c[k8 * 4 + 2] = t4[2]; c[k8 * 4 + 3] = t4[3];
      }
      float mx = -3.0e38f;
#pragma unroll
      for (int k = 0; k < KC; k++) mx = fmaxf(mx, vsh[k] - c[k]);
      float s = 0.f;
#pragma unroll
      for (int k = 0; k < KC; k++) s += expf((vsh[k] - c[k] - mx) * IEPS);
      u[r] = EPS * logp - mx - EPS * logf(s);
#pragma unroll
      for (int k = 0; k < KC; k++) lm[k] = fmaxf(lm[k], (u[r] - c[k]) * IEPS);
    }
#pragma unroll
    for (int k = 0; k < KC; k++) {
      float x = waveAllMax(lm[k]);
      if (lane == 0) wred[k][wid] = x;
    }
    __syncthreads();
    if (tid < KC) {
      float bm = -3.0e38f;
      for (int w = 0; w < 16; w++) bm = fmaxf(bm, wred[tid][w]);
      bmf[tid] = bm;
    }
    __syncthreads();
    float es[KC];
#pragma unroll
    for (int k = 0; k < KC; k++) es[k] = 0.f;
#pragma unroll 1
    for (int r = 0; r < 4; r++) {
      const float* crow = cb + (size_t)(r * 1024 + tid) * KC;
#pragma unroll
      for (int k8 = 0; k8 < 8; k8++) {
        f32x4 t4 = *(const f32x4*)(crow + k8 * 4);
#pragma unroll
        for (int jj = 0; jj < 4; jj++) {
          int k = k8 * 4 + jj;
          es[k] += expf((u[r] - t4[jj]) * IEPS - bmf[k]);
        }
      }
    }
#pragma unroll
    for (int k = 0; k < KC; k++) {
      float e = waveAllSum(es[k]);
      if (lane == 0) wred[k][wid] = e;
    }
    __syncthreads();
    if (tid < KC) {
      float s = 0.f;
      for (int w = 0; w < 16; w++) s += wred[tid][w];
      vsh[tid] = EPS * logq - EPS * (bmf[tid] + logf(s));
    }
    __syncthreads();
  }
  float part = 0.f;
#pragma unroll 1
  for (int r = 0; r < 4; r++) {
    int n = r * 1024 + tid;
    const float* crow = cb + (size_t)n * KC;
    float lsev = lseArr[(size_t)b * NP + n];
#pragma unroll
    for (int k = 0; k < KC; k++) {
      float gamma = expf((u[r] + vsh[k] - crow[k]) * IEPS);
      float logsm = LSm[((size_t)b * KC + k) * NP + n] - lsev;
      part += gamma * logsm;
    }
  }
  part *= (float)NP;
  part = waveReduceSum(part);
  __shared__ float red[16];
  if (lane == 0) red[wid] = part;
  __syncthreads();
  if (tid == 0) {
    float t = 0.f;
    for (int w = 0; w < 16; w++) t += red[w];
    atomicAdd(out0, -t / (float)(BB * NP));
  }
}

// ---------------- tiled f32 conv1x1 GEMM (projector head, N=32 tiny)
template<int BM, int BN, int BK, int TM, int TN, bool BNRELU>
__global__ __launch_bounds__(256) void gemm_conv(
    const float* __restrict__ W, const float* __restrict__ bias,
    const float* __restrict__ X, float* __restrict__ Y,
    const float* __restrict__ bnscale, const float* __restrict__ bnshift,
    int M, int K, int N) {
  __shared__ float As[BK][BM + 4];
  __shared__ float Xs[BK][BN + 4];
  const int b = blockIdx.z;
  const int m0 = blockIdx.y * BM;
  const int n0 = blockIdx.x * BN;
  const int tid = threadIdx.x;
  const int tx = tid % (BN / TN);
  const int ty = tid / (BN / TN);
  const float* Xb = X + (size_t)b * K * N;
  float acc[TM][TN];
#pragma unroll
  for (int i = 0; i < TM; i++)
#pragma unroll
    for (int j = 0; j < TN; j++) acc[i][j] = 0.f;

  for (int k0 = 0; k0 < K; k0 += BK) {
    for (int i = tid; i < BM * BK; i += 256) {
      int r = i / BK, c = i % BK;
      As[c][r] = W[(size_t)(m0 + r) * K + k0 + c];
    }
    for (int i = tid; i < BK * BN; i += 256) {
      int r = i / BN, c = i % BN;
      float x = Xb[(size_t)(k0 + r) * N + n0 + c];
      if (BNRELU) x = fmaxf(fmaf(x, bnscale[k0 + r], bnshift[k0 + r]), 0.f);
      Xs[r][c] = x;
    }
    __syncthreads();
#pragma unroll 4
    for (int kk = 0; kk < BK; kk++) {
      float ra[TM], rb[TN];
#pragma unroll
      for (int i = 0; i < TM; i++) ra[i] = As[kk][ty * TM + i];
#pragma unroll
      for (int j = 0; j < TN; j++) rb[j] = Xs[kk][tx * TN + j];
#pragma unroll
      for (int i = 0; i < TM; i++)
#pragma unroll
        for (int j = 0; j < TN; j++) acc[i][j] = fmaf(ra[i], rb[j], acc[i][j]);
    }
    __syncthreads();
  }
#pragma unroll
  for (int i = 0; i < TM; i++) {
    float bm = bias[m0 + ty * TM + i];
#pragma unroll
    for (int j = 0; j < TN; j++)
      Y[((size_t)b * M + m0 + ty * TM + i) * N + n0 + tx * TN + j] = acc[i][j] + bm;
  }
}

// ---------------- tiny MLP gemm
template<bool BNRELU>
__global__ __launch_bounds__(256) void mlp_gemm(
    const float* __restrict__ W, const float* __restrict__ bias,
    const float* __restrict__ in, float* __restrict__ out,
    const float* __restrict__ sc, const float* __restrict__ sh, int M, int K) {
  int idx = blockIdx.x * 256 + threadIdx.x;
  if (idx >= BB * M) return;
  int s = idx / M, jj = idx % M;
  const float4* ip = (const float4*)(in + (size_t)s * K);
  const float4* wp = (const float4*)(W + (size_t)jj * K);
  float acc = 0.f;
  for (int c4 = 0; c4 < K / 4; c4++) {
    float4 x = ip[c4];
    float4 w = wp[c4];
    if (BNRELU) {
      int cb = c4 * 4;
      x.x = fmaxf(fmaf(x.x, sc[cb + 0], sh[cb + 0]), 0.f);
      x.y = fmaxf(fmaf(x.y, sc[cb + 1], sh[cb + 1]), 0.f);
      x.z = fmaxf(fmaf(x.z, sc[cb + 2], sh[cb + 2]), 0.f);
      x.w = fmaxf(fmaf(x.w, sc[cb + 3], sh[cb + 3]), 0.f);
    }
    acc += x.x * w.x + x.y * w.y + x.z * w.z + x.w * w.w;
  }
  out[idx] = acc + bias[jj];
}

__global__ __launch_bounds__(256) void mlp_bnstats(
    const float* __restrict__ mat, const float* __restrict__ g, const float* __restrict__ beta,
    float* __restrict__ scale, float* __restrict__ shift, int M) {
  int j = blockIdx.x * 256 + threadIdx.x;
  if (j >= M) return;
  float s = 0.f, sq = 0.f;
  for (int si = 0; si < BB; si++) { float v = mat[si * M + j]; s += v; sq += v * v; }
  float mean = s / (float)BB;
  float var = sq / (float)BB - mean * mean;
  float sc = g[j] / sqrtf(var + BN_EPS);
  scale[j] = sc; shift[j] = beta[j] - mean * sc;
}

// ---------------- launch ----------------
extern "C" void kernel_launch(void* const* d_in, const int* in_sizes, int n_in,
                              void* d_out, int out_size, void* d_ws, size_t ws_size,
                              hipStream_t stream) {
  const float* feat = (const float*)d_in[0];
  const float* cw1 = (const float*)d_in[1];  const float* cb1 = (const float*)d_in[2];
  const float* cg1 = (const float*)d_in[3];  const float* ct1 = (const float*)d_in[4];
  const float* cw2 = (const float*)d_in[5];  const float* cb2 = (const float*)d_in[6];
  const float* cg2 = (const float*)d_in[7];  const float* ct2 = (const float*)d_in[8];
  const float* cw3 = (const float*)d_in[9];  const float* cb3 = (const float*)d_in[10];
  const float* pw1 = (const float*)d_in[11]; const float* pb1 = (const float*)d_in[12];
  const float* pg1 = (const float*)d_in[13]; const float* pt1 = (const float*)d_in[14];
  const float* pw2 = (const float*)d_in[15]; const float* pb2 = (const float*)d_in[16];
  const float* pg2 = (const float*)d_in[17]; const float* pt2 = (const float*)d_in[18];
  const float* pw3 = (const float*)d_in[19]; const float* pb3 = (const float*)d_in[20];
  const float* mw1 = (const float*)d_in[21]; const float* mb1 = (const float*)d_in[22];
  const float* mg1 = (const float*)d_in[23]; const float* mt1 = (const float*)d_in[24];
  const float* mw2 = (const float*)d_in[25]; const float* mb2 = (const float*)d_in[26];
  const float* mg2 = (const float*)d_in[27]; const float* mt2 = (const float*)d_in[28];
  const float* mw3 = (const float*)d_in[29]; const float* mb3 = (const float*)d_in[30];
  float* out = (float*)d_out;

  // ---- workspace layout (bytes, 256B aligned) ----
  // Total footprint kept < 143 MiB (round-1-proven ws bound). Y1's 64 MB region
  // is dead after GEMM2; all post-GEMM2 buffers alias into it.
  char* p = (char*)d_ws;
  size_t off = 0;
  auto alloc = [&](size_t bytes) { char* r = p + off; off = (off + bytes + 255) & ~(size_t)255; return r; };
  float* Y1 = (float*)alloc(67108864);   // [8][512][4096] f32
  float* Y2 = (float*)alloc(67108864);
  u16* W1H = (u16*)alloc(1048576); u16* W1M = (u16*)alloc(1048576); u16* W1L = (u16*)alloc(1048576);
  u16* W2H = (u16*)alloc(524288);  u16* W2M = (u16*)alloc(524288);  u16* W2L = (u16*)alloc(524288);
  u16* W3H = (u16*)alloc(32768);   u16* W3M = (u16*)alloc(32768);   u16* W3L = (u16*)alloc(32768);
  float* SC1  = (float*)alloc(2048); float* SH1 = (float*)alloc(2048);
  float* SC2  = (float*)alloc(2048); float* SH2 = (float*)alloc(2048);
  float* PSC1 = (float*)alloc(2048); float* PSH1 = (float*)alloc(2048);
  float* PSC2 = (float*)alloc(2048); float* PSH2 = (float*)alloc(2048);
  float* MSC1 = (float*)alloc(2048); float* MSH1 = (float*)alloc(2048);
  float* MSC2 = (float*)alloc(2048); float* MSH2 = (float*)alloc(2048);
  // ---- sub-arena inside Y1's region: everything here is first written AFTER
  // GEMM2 (Y1's last reader) completes ----
  char* q = (char*)Y1;
  size_t qoff = 0;
  auto qalloc = [&](size_t bytes) { char* r = q + qoff; qoff = (qoff + bytes + 255) & ~(size_t)255; return r; };
  float* LSC  = (float*)qalloc(4194304);  // [8][32][4096], written by GEMM3
  float* SCRB = (float*)qalloc(4194304);  // score
  float* LSE  = (float*)qalloc(131072);
  float* NFN  = (float*)qalloc(131072);
  float* NMUN = (float*)qalloc(1024);
  float* GMAX = (float*)qalloc(32768);
  float* MH1  = (float*)qalloc(16384);
  float* MH2  = (float*)qalloc(16384);
  float* T1   = (float*)qalloc(524288);
  float* T2   = (float*)qalloc(524288);
  // contiguous memset region: PIRAW | VLAD | COSTD (memset AFTER GEMM2 in stream)
  char* MS = qalloc(1024 + 1048576 + 4194304);
  float* PIRAW = (float*)MS;
  float* VLAD  = (float*)(MS + 1024);
  float* COSTD = (float*)(MS + 1024 + 1048576);

  hipMemsetAsync(d_out, 0, sizeof(float), stream);

  float logp = logf(1.0f / NP + 1e-8f);
  float logq = logf(1.0f / KC + 1e-8f);
  dim3 blk(256);

  // weight permute + 3-split
  convW3<128><<<dim3(4, 32), blk, 0, stream>>>(cw1, W1H, W1M, W1L, 1024);
  convW3<128><<<dim3(4, 16), blk, 0, stream>>>(cw2, W2H, W2M, W2L, 512);
  convW3<32><<<dim3(1, 16), blk, 0, stream>>>(cw3, W3H, W3M, W3L, 512);

  // score head: bf16x3 MFMA (f32-equivalent)
  gemm_mfma3<128, 4, 4, 4, 2, false><<<dim3(128, 1, 8), blk, 0, stream>>>(
      W1H, W1M, W1L, cb1, feat, nullptr, nullptr, Y1, 1024, 512);
  bnstats<<<dim3(512), blk, 0, stream>>>(Y1, cg1, ct1, SC1, SH1, 512, NP);
  gemm_mfma3<128, 4, 4, 4, 2, true><<<dim3(128, 1, 8), blk, 0, stream>>>(
      W2H, W2M, W2L, cb2, Y1, SC1, SH1, Y2, 512, 512);
  bnstats<<<dim3(512), blk, 0, stream>>>(Y2, cg2, ct2, SC2, SH2, 512, NP);
  // Y1 is now dead -> zero the aliased accumulation buffers inside it
  hipMemsetAsync(MS, 0, 1024 + 1048576 + 4194304, stream);
  gemm_mfma3<32, 1, 2, 2, 1, true><<<dim3(32, 1, 8), blk, 0, stream>>>(
      W3H, W3M, W3L, cb3, Y2, SC2, SH2, LSC, 512, 32);

  // softmax + pi + lse
  softmax_pi<<<dim3(BB * NP / 256), blk, 0, stream>>>(LSC, SCRB, LSE, PIRAW);

  // vlad
  vlad_accum<<<dim3(8, DD / 128, BB), blk, 0, stream>>>(feat, SCRB, VLAD);
  vlad_fin<<<dim3(BB * DD / 256), blk, 0, stream>>>(VLAD, PIRAW, GMAX);
  nmu_norm_k<<<dim3(BB), blk, 0, stream>>>(VLAD, NMUN);
  nf_norm_k<<<dim3(BB * NP / 256), blk, 0, stream>>>(feat, NFN);

  // cost
  cost_accum<<<dim3(4, NP / 128, BB), blk, 0, stream>>>(feat, VLAD, COSTD);
  cost_fin<<<dim3(BB * NP * KC / 256), blk, 0, stream>>>(COSTD, NFN, NMUN);

  // fused sinkhorn (25 fixed iters) + loss
  sinkhorn_loss<<<dim3(BB), dim3(1024), 0, stream>>>(COSTD, LSC, LSE, out, logp, logq);

  // predictor MLP on max-pooled vlad
  mlp_gemm<false><<<dim3(BB * HH / 256), blk, 0, stream>>>(mw1, mb1, GMAX, MH1, nullptr, nullptr, HH, DD);
  mlp_bnstats<<<dim3(2), blk, 0, stream>>>(MH1, mg1, mt1, MSC1, MSH1, HH);
  mlp_gemm<true><<<dim3(BB * HH / 256), blk, 0, stream>>>(mw2, mb2, MH1, MH2, MSC1, MSH1, HH, HH);
  mlp_bnstats<<<dim3(2), blk, 0, stream>>>(MH2, mg2, mt2, MSC2, MSH2, HH);
  mlp_gemm<true><<<dim3(BB * PP / 256), blk, 0, stream>>>(mw3, mb3, MH2, out + 1 + BB * PP * KC, MSC2, MSH2, PP, HH);

  // projector conv head on vlad (N=32, f32)
  gemm_conv<64, 32, 16, 4, 2, false><<<dim3(1, HH / 64, BB), blk, 0, stream>>>(pw1, pb1, VLAD, T1, nullptr, nullptr, HH, DD, KC);
  bnstats<<<dim3(512), blk, 0, stream>>>(T1, pg1, pt1, PSC1, PSH1, HH, KC);
  gemm_conv<64, 32, 16, 4, 2, true><<<dim3(1, HH / 64, BB), blk, 0, stream>>>(pw2, pb2, T1, T2, PSC1, PSH1, HH, HH, KC);
  bnstats<<<dim3(512), blk, 0, stream>>>(T2, pg2, pt2, PSC2, PSH2, HH, KC);
  gemm_conv<64, 32, 16, 4, 2, true><<<dim3(1, PP / 64, BB), blk, 0, stream>>>(pw3, pb3, T2, out + 1, PSC2, PSH2, PP, HH, KC);
}

// Round 5
// 1810.376 us; speedup vs baseline: 1.4765x; 1.4765x over previous
//
#include <hip/hip_runtime.h>
#include <cmath>

#define BB 8
#define DD 1024
#define NP 4096
#define KC 32
#define HH 512
#define PP 128
#define NJB 16          // sinkhorn blocks per batch
#define BN_EPS 1e-5f

typedef unsigned short u16;
typedef short s16x8 __attribute__((ext_vector_type(8)));
typedef float f32x4 __attribute__((ext_vector_type(4)));

// ---------------- wave helpers ----------------
__device__ __forceinline__ float waveReduceSum(float v) {
#pragma unroll
  for (int o = 32; o > 0; o >>= 1) v += __shfl_down(v, o, 64);
  return v;
}
__device__ __forceinline__ float waveAllMax(float v) {
#pragma unroll
  for (int o = 32; o > 0; o >>= 1) v = fmaxf(v, __shfl_xor(v, o, 64));
  return v;
}
__device__ __forceinline__ float waveAllSum(float v) {
#pragma unroll
  for (int o = 32; o > 0; o >>= 1) v += __shfl_xor(v, o, 64);
  return v;
}

// ---------------- bf16 3-way split: y = h + m + l + O(2^-24 |y|) ----------
__device__ __forceinline__ void split3(float y, short& h, short& m, short& l) {
  unsigned uy = __float_as_uint(y);
  h = (short)(uy >> 16);
  float r1 = y - __uint_as_float(uy & 0xFFFF0000u);
  unsigned um = __float_as_uint(r1);
  m = (short)(um >> 16);
  float r2 = r1 - __uint_as_float(um & 0xFFFF0000u);
  l = (short)(__float_as_uint(r2) >> 16);
}

// ---------------- W pre-permute + 3-split: block (mt,kc): [q][m][j] = W[mt*BM+m][kc*32+q*8+j]
template<int BM>
__global__ __launch_bounds__(256) void convW3(
    const float* __restrict__ W, u16* __restrict__ hb, u16* __restrict__ mb, u16* __restrict__ lb,
    int K) {
  int mt = blockIdx.x, kc = blockIdx.y, KCH = gridDim.y;
  const int AU = BM * 4;
  for (int u = threadIdx.x; u < AU; u += 256) {
    int q = u / BM, m = u % BM;
    const float* wp = W + (size_t)(mt * BM + m) * K + kc * 32 + q * 8;
    s16x8 hv, mv, lv;
#pragma unroll
    for (int j = 0; j < 8; j++) {
      short h, mm, l; split3(wp[j], h, mm, l);
      hv[j] = h; mv[j] = mm; lv[j] = l;
    }
    size_t ob = ((size_t)(mt * KCH + kc)) * (size_t)(BM * 32) + (size_t)u * 8;
    *(s16x8*)(hb + ob) = hv;
    *(s16x8*)(mb + ob) = mv;
    *(s16x8*)(lb + ob) = lv;
  }
}

// ---------------- bf16x3 MFMA GEMM (f32-equivalent): Y[b,m,n] = sum_k W[m,k]*f(X[b,k,n]) + bias[m]
template<int BM, int MBLK, int MT, int NT, int WM, bool BNRELU>
__global__ __launch_bounds__(256) void gemm_mfma3(
    const u16* __restrict__ wh, const u16* __restrict__ wmid, const u16* __restrict__ wl,
    const float* __restrict__ bias, const float* __restrict__ X,
    const float* __restrict__ bnsc, const float* __restrict__ bnsh,
    float* __restrict__ Y, int K, int M) {
  __shared__ s16x8 AhS[BM * 4], AmS[BM * 4], AlS[BM * 4];
  __shared__ s16x8 BhS[512], BmS[512], BlS[512];
  const int KCH = K / 32;
  const int tid = threadIdx.x;
  const int bz = blockIdx.z;
  int bid = blockIdx.x;
  int xs = bid & 7, rr = bid >> 3;
  int m_idx = rr % MBLK;
  int n_idx = xs + 8 * (rr / MBLK);

  const int w = tid >> 6, l = tid & 63, q = l >> 4, col = l & 15;
  const int wm = (WM == 1) ? 0 : (w >> 1);
  const int wn = (WM == 1) ? w : (w & 1);

  f32x4 acc[MT][NT];
#pragma unroll
  for (int i = 0; i < MT; i++)
#pragma unroll
    for (int j = 0; j < NT; j++) { acc[i][j][0] = 0.f; acc[i][j][1] = 0.f; acc[i][j][2] = 0.f; acc[i][j][3] = 0.f; }

  const short* Ah = (const short*)AhS;
  const short* Am = (const short*)AmS;
  const short* Al = (const short*)AlS;
  const short* Bh = (const short*)BhS;
  const short* Bm = (const short*)BmS;
  const short* Bl = (const short*)BlS;

  for (int kc = 0; kc < KCH; kc++) {
    {
      size_t ab = ((size_t)(m_idx * KCH + kc)) * (size_t)(BM * 32);
      const s16x8* awh = (const s16x8*)(wh + ab);
      const s16x8* awm = (const s16x8*)(wmid + ab);
      const s16x8* awl = (const s16x8*)(wl + ab);
      for (int u = tid; u < BM * 4; u += 256) { AhS[u] = awh[u]; AmS[u] = awm[u]; AlS[u] = awl[u]; }
    }
    for (int u = tid; u < 512; u += 256) {
      int qq = u >> 7, n = u & 127;
      const float* fp = X + (size_t)bz * K * NP + (size_t)(kc * 32 + qq * 8) * NP + (size_t)n_idx * 128 + n;
      s16x8 hv, mv, lv;
#pragma unroll
      for (int j = 0; j < 8; j++) {
        float y = fp[(size_t)j * NP];
        if (BNRELU) y = fmaxf(fmaf(y, bnsc[kc * 32 + qq * 8 + j], bnsh[kc * 32 + qq * 8 + j]), 0.f);
        short h, mm, ll; split3(y, h, mm, ll);
        hv[j] = h; mv[j] = mm; lv[j] = ll;
      }
      BhS[u] = hv; BmS[u] = mv; BlS[u] = lv;
    }
    __syncthreads();
    s16x8 ah[MT], am[MT], al[MT];
#pragma unroll
    for (int i = 0; i < MT; i++) {
      int off = (q * BM + wm * (MT * 16) + i * 16 + col) * 8;
      ah[i] = *(const s16x8*)(Ah + off);
      am[i] = *(const s16x8*)(Am + off);
      al[i] = *(const s16x8*)(Al + off);
    }
#pragma unroll
    for (int j = 0; j < NT; j++) {
      int offb = (q * 128 + wn * (NT * 16) + j * 16 + col) * 8;
      s16x8 bh = *(const s16x8*)(Bh + offb);
      s16x8 bm = *(const s16x8*)(Bm + offb);
      s16x8 bl = *(const s16x8*)(Bl + offb);
#pragma unroll
      for (int i = 0; i < MT; i++) {
        acc[i][j] = __builtin_amdgcn_mfma_f32_16x16x32_bf16(ah[i], bh, acc[i][j], 0, 0, 0);
        acc[i][j] = __builtin_amdgcn_mfma_f32_16x16x32_bf16(ah[i], bm, acc[i][j], 0, 0, 0);
        acc[i][j] = __builtin_amdgcn_mfma_f32_16x16x32_bf16(am[i], bh, acc[i][j], 0, 0, 0);
        acc[i][j] = __builtin_amdgcn_mfma_f32_16x16x32_bf16(ah[i], bl, acc[i][j], 0, 0, 0);
        acc[i][j] = __builtin_amdgcn_mfma_f32_16x16x32_bf16(am[i], bm, acc[i][j], 0, 0, 0);
        acc[i][j] = __builtin_amdgcn_mfma_f32_16x16x32_bf16(al[i], bh, acc[i][j], 0, 0, 0);
      }
    }
    __syncthreads();
  }
#pragma unroll
  for (int i = 0; i < MT; i++) {
#pragma unroll
    for (int r = 0; r < 4; r++) {
      int m = m_idx * BM + wm * (MT * 16) + i * 16 + q * 4 + r;
      float bv = bias[m];
#pragma unroll
      for (int j = 0; j < NT; j++) {
        int n = n_idx * 128 + wn * (NT * 16) + j * 16 + col;
        Y[((size_t)bz * M + m) * 4096 + n] = acc[i][j][r] + bv;
      }
    }
  }
}

// ---------------- BN (training, batch stats over B and N) per channel
__global__ __launch_bounds__(256) void bnstats(
    const float* __restrict__ Y, const float* __restrict__ g, const float* __restrict__ beta,
    float* __restrict__ scale, float* __restrict__ shift, int C, int N) {
  int c = blockIdx.x;
  float s = 0.f, sq = 0.f;
  for (int b = 0; b < BB; b++) {
    const float* p = Y + ((size_t)b * C + c) * N;
    for (int n = threadIdx.x; n < N; n += 256) { float v = p[n]; s += v; sq += v * v; }
  }
  __shared__ float shs[4], shq[4];
  int lane = threadIdx.x & 63, wid = threadIdx.x >> 6;
  s = waveReduceSum(s); sq = waveReduceSum(sq);
  if (lane == 0) { shs[wid] = s; shq[wid] = sq; }
  __syncthreads();
  if (threadIdx.x == 0) {
    float S = shs[0] + shs[1] + shs[2] + shs[3];
    float Q = shq[0] + shq[1] + shq[2] + shq[3];
    float cnt = (float)(BB * N);
    float mean = S / cnt;
    float var = Q / cnt - mean * mean;
    float sc = g[c] / sqrtf(var + BN_EPS);
    scale[c] = sc; shift[c] = beta[c] - mean * sc;
  }
}

// ---------------- softmax over K (axis=1), write score, lse per (b,n), pi partial sums
__global__ __launch_bounds__(256) void softmax_pi(
    const float* __restrict__ LSm, float* __restrict__ score,
    float* __restrict__ lseArr, float* __restrict__ pi_raw) {
  int gidx = blockIdx.x * 256 + threadIdx.x;
  int b = gidx / NP, n = gidx % NP;
  const float* p = LSm + (size_t)b * KC * NP + n;
  float v[KC];
  float m = -1e30f;
#pragma unroll
  for (int k = 0; k < KC; k++) { v[k] = p[(size_t)k * NP]; m = fmaxf(m, v[k]); }
  float s = 0.f;
#pragma unroll
  for (int k = 0; k < KC; k++) { v[k] = expf(v[k] - m); s += v[k]; }
  float inv = 1.f / s;
  float* qq = score + (size_t)b * KC * NP + n;
#pragma unroll
  for (int k = 0; k < KC; k++) { v[k] *= inv; qq[(size_t)k * NP] = v[k]; }
  lseArr[gidx] = m + logf(s);
  __shared__ float ps[KC];
  if (threadIdx.x < KC) ps[threadIdx.x] = 0.f;
  __syncthreads();
  int lane = threadIdx.x & 63;
#pragma unroll
  for (int k = 0; k < KC; k++) {
    float w = waveReduceSum(v[k]);
    if (lane == 0) atomicAdd(&ps[k], w);
  }
  __syncthreads();
  if (threadIdx.x < KC) atomicAdd(&pi_raw[b * KC + threadIdx.x], ps[threadIdx.x]);
}

// ---------------- vlad accumulation (split over n, atomic)
__global__ __launch_bounds__(256) void vlad_accum(
    const float* __restrict__ feat, const float* __restrict__ score, float* __restrict__ vlad) {
  const int SPLIT_LEN = NP / 8;
  int sp = blockIdx.x, dt = blockIdx.y, b = blockIdx.z;
  int d0 = dt * 128;
  int n_start = sp * SPLIT_LEN;
  __shared__ float As[32][132];
  __shared__ float Bs[32][36];
  int tid = threadIdx.x;
  int tx = tid % 16;
  int ty = tid / 16;
  float acc[8][2] = {};
  const float* fb = feat + (size_t)b * DD * NP;
  const float* sb = score + (size_t)b * KC * NP;
  for (int nc = 0; nc < SPLIT_LEN; nc += 32) {
    int n0 = n_start + nc;
    for (int i = tid; i < 128 * 32; i += 256) {
      int r = i >> 5, c = i & 31;
      As[c][r] = fb[(size_t)(d0 + r) * NP + n0 + c];
    }
    for (int i = tid; i < 32 * 32; i += 256) {
      int r = i >> 5, c = i & 31;
      Bs[c][r] = sb[(size_t)r * NP + n0 + c];
    }
    __syncthreads();
#pragma unroll 4
    for (int kk = 0; kk < 32; kk++) {
      float ra[8], rb[2];
#pragma unroll
      for (int i = 0; i < 8; i++) ra[i] = As[kk][ty * 8 + i];
      rb[0] = Bs[kk][tx * 2]; rb[1] = Bs[kk][tx * 2 + 1];
#pragma unroll
      for (int i = 0; i < 8; i++) { acc[i][0] = fmaf(ra[i], rb[0], acc[i][0]); acc[i][1] = fmaf(ra[i], rb[1], acc[i][1]); }
    }
    __syncthreads();
  }
#pragma unroll
  for (int i = 0; i < 8; i++)
#pragma unroll
    for (int j = 0; j < 2; j++)
      atomicAdd(&vlad[((size_t)b * DD + d0 + ty * 8 + i) * KC + tx * 2 + j], acc[i][j]);
}

__global__ __launch_bounds__(256) void vlad_fin(
    float* __restrict__ vlad, const float* __restrict__ pi_raw, float* __restrict__ gmax) {
  int idx = blockIdx.x * 256 + threadIdx.x;
  int b = idx / DD;
  float* p = vlad + (size_t)idx * KC;
  const float* pr = pi_raw + b * KC;
  float gm = -1e30f;
#pragma unroll
  for (int k = 0; k < KC; k++) {
    float v = p[k] / fmaxf(pr[k], 1e-4f);
    p[k] = v;
    gm = fmaxf(gm, v);
  }
  gmax[idx] = gm;
}

__global__ __launch_bounds__(256) void nmu_norm_k(
    const float* __restrict__ vlad, float* __restrict__ nmun) {
  int b = blockIdx.x, tid = threadIdx.x;
  int k = tid & 31, dg = tid >> 5;
  float s = 0.f;
  for (int d = dg * 128; d < dg * 128 + 128; d++) {
    float v = vlad[((size_t)b * DD + d) * KC + k]; s += v * v;
  }
  __shared__ float sh[8][32];
  sh[dg][k] = s;
  __syncthreads();
  if (tid < 32) {
    float t = 0.f;
    for (int i = 0; i < 8; i++) t += sh[i][tid];
    nmun[b * KC + tid] = fmaxf(sqrtf(t), 1e-12f);
  }
}

__global__ __launch_bounds__(256) void nf_norm_k(
    const float* __restrict__ feat, float* __restrict__ nfn) {
  int idx = blockIdx.x * 256 + threadIdx.x;
  int b = idx / NP, n = idx % NP;
  const float* p = feat + (size_t)b * DD * NP + n;
  float s = 0.f;
  for (int d = 0; d < DD; d++) { float v = p[(size_t)d * NP]; s += v * v; }
  nfn[idx] = fmaxf(sqrtf(s), 1e-12f);
}

// ---------------- cost dot accumulation (split over d, atomic)
__global__ __launch_bounds__(256) void cost_accum(
    const float* __restrict__ feat, const float* __restrict__ vlad, float* __restrict__ costd) {
  int sp = blockIdx.x, nt = blockIdx.y, b = blockIdx.z;
  int n0 = nt * 128;
  int d_start = sp * (DD / 4);
  __shared__ float As[32][132];
  __shared__ float Bs[32][36];
  int tid = threadIdx.x;
  int tx = tid % 16;
  int ty = tid / 16;
  float acc[8][2] = {};
  const float* fb = feat + (size_t)b * DD * NP;
  const float* vb = vlad + (size_t)b * DD * KC;
  for (int dc = 0; dc < DD / 4; dc += 32) {
    int dd0 = d_start + dc;
    for (int i = tid; i < 32 * 128; i += 256) {
      int r = i >> 7, c = i & 127;
      As[r][c] = fb[(size_t)(dd0 + r) * NP + n0 + c];
    }
    for (int i = tid; i < 32 * 32; i += 256) {
      int r = i >> 5, c = i & 31;
      Bs[r][c] = vb[(size_t)(dd0 + r) * KC + c];
    }
    __syncthreads();
#pragma unroll 4
    for (int kk = 0; kk < 32; kk++) {
      float ra[8], rb[2];
#pragma unroll
      for (int i = 0; i < 8; i++) ra[i] = As[kk][ty * 8 + i];
      rb[0] = Bs[kk][tx * 2]; rb[1] = Bs[kk][tx * 2 + 1];
#pragma unroll
      for (int i = 0; i < 8; i++) { acc[i][0] = fmaf(ra[i], rb[0], acc[i][0]); acc[i][1] = fmaf(ra[i], rb[1], acc[i][1]); }
    }
    __syncthreads();
  }
#pragma unroll
  for (int i = 0; i < 8; i++)
#pragma unroll
    for (int j = 0; j < 2; j++)
      atomicAdd(&costd[((size_t)b * NP + n0 + ty * 8 + i) * KC + tx * 2 + j], acc[i][j]);
}

__global__ __launch_bounds__(256) void cost_fin(
    float* __restrict__ costd, const float* __restrict__ nfn, const float* __restrict__ nmun) {
  size_t idx = (size_t)blockIdx.x * 256 + threadIdx.x;
  int k = (int)(idx & 31);
  size_t nn = idx >> 5;
  int n = (int)(nn % NP);
  int b = (int)(nn / NP);
  float dot = costd[idx];
  costd[idx] = 2.f - 2.f * dot / (nfn[b * NP + n] * nmun[b * KC + k]);
}

// ---------------- sinkhorn iteration t (1..25). G[t-1][b][j][k] = (blockmax, blocksum) of (u-c)/eps
__global__ __launch_bounds__(256) void sinkhorn_iter(
    const float* __restrict__ cost, float* __restrict__ G, int t, float logp, float logq) {
  const float EPS = 1e-3f, IEPS = 1000.f;
  int b = blockIdx.x / NJB, j = blockIdx.x % NJB;
  int tid = threadIdx.x;
  int n = j * 256 + tid;
  __shared__ float vsh[KC];
  __shared__ float wm[KC][4];
  __shared__ float wsum[KC][4];
  if (tid < KC) {
    float v = 0.f;
    if (t > 1) {
      const float* Gp = G + (((size_t)(t - 2) * BB + b) * NJB) * KC * 2;
      float m = -1e30f;
      for (int jj = 0; jj < NJB; jj++) m = fmaxf(m, Gp[(jj * KC + tid) * 2]);
      float s = 0.f;
      for (int jj = 0; jj < NJB; jj++) s += Gp[(jj * KC + tid) * 2 + 1] * expf(Gp[(jj * KC + tid) * 2] - m);
      v = EPS * logq - EPS * (m + logf(s));
    }
    vsh[tid] = v;
  }
  __syncthreads();
  const float* crow = cost + ((size_t)b * NP + n) * KC;
  float c[KC];
#pragma unroll
  for (int k = 0; k < KC; k++) c[k] = crow[k];
  float m = -1e30f;
#pragma unroll
  for (int k = 0; k < KC; k++) m = fmaxf(m, vsh[k] - c[k]);
  float s = 0.f;
#pragma unroll
  for (int k = 0; k < KC; k++) s += expf((vsh[k] - c[k] - m) * IEPS);
  float u = EPS * logp - m - EPS * logf(s);
  int lane = tid & 63, wid = tid >> 6;
#pragma unroll
  for (int k = 0; k < KC; k++) {
    float x = waveAllMax((u - c[k]) * IEPS);
    if (lane == 0) wm[k][wid] = x;
  }
  __syncthreads();
#pragma unroll
  for (int k = 0; k < KC; k++) {
    float bm = fmaxf(fmaxf(wm[k][0], wm[k][1]), fmaxf(wm[k][2], wm[k][3]));
    float e = waveAllSum(expf((u - c[k]) * IEPS - bm));
    if (lane == 0) wsum[k][wid] = e;
  }
  __syncthreads();
  if (tid < KC) {
    float bm = fmaxf(fmaxf(wm[tid][0], wm[tid][1]), fmaxf(wm[tid][2], wm[tid][3]));
    float s4 = wsum[tid][0] + wsum[tid][1] + wsum[tid][2] + wsum[tid][3];
    float* Gp = G + ((((size_t)(t - 1) * BB + b) * NJB + j) * KC + tid) * 2;
    Gp[0] = bm; Gp[1] = s4;
  }
}

// ---------------- loss: gamma from (u25 from v24, v25); -mean(sum_k NP*gamma*logsm)
__global__ __launch_bounds__(256) void loss_kernel(
    const float* __restrict__ cost, const float* __restrict__ G,
    const float* __restrict__ LSm, const float* __restrict__ lseArr,
    float* __restrict__ out0, float logp, float logq) {
  const float EPS = 1e-3f, IEPS = 1000.f;
  int b = blockIdx.x / NJB, j = blockIdx.x % NJB;
  int tid = threadIdx.x;
  int n = j * 256 + tid;
  __shared__ float v24[KC], v25[KC];
  if (tid < 2 * KC) {
    int which = tid / KC, k = tid % KC;
    const float* Gp = G + (((size_t)(23 + which) * BB + b) * NJB) * KC * 2;
    float m = -1e30f;
    for (int jj = 0; jj < NJB; jj++) m = fmaxf(m, Gp[(jj * KC + k) * 2]);
    float s = 0.f;
    for (int jj = 0; jj < NJB; jj++) s += Gp[(jj * KC + k) * 2 + 1] * expf(Gp[(jj * KC + k) * 2] - m);
    float v = EPS * logq - EPS * (m + logf(s));
    if (which) v25[k] = v; else v24[k] = v;
  }
  __syncthreads();
  const float* crow = cost + ((size_t)b * NP + n) * KC;
  float c[KC];
#pragma unroll
  for (int k = 0; k < KC; k++) c[k] = crow[k];
  float m = -1e30f;
#pragma unroll
  for (int k = 0; k < KC; k++) m = fmaxf(m, v24[k] - c[k]);
  float s = 0.f;
#pragma unroll
  for (int k = 0; k < KC; k++) s += expf((v24[k] - c[k] - m) * IEPS);
  float u = EPS * logp - m - EPS * logf(s);
  float lsev = lseArr[(size_t)b * NP + n];
  float part = 0.f;
#pragma unroll
  for (int k = 0; k < KC; k++) {
    float gamma = expf((u + v25[k] - c[k]) * IEPS);
    float logsm = LSm[((size_t)b * KC + k) * NP + n] - lsev;
    part += gamma * logsm;
  }
  part *= (float)NP;
  int lane = tid & 63, wid = tid >> 6;
  part = waveReduceSum(part);
  __shared__ float red[4];
  if (lane == 0) red[wid] = part;
  __syncthreads();
  if (tid == 0) {
    float tt = red[0] + red[1] + red[2] + red[3];
    atomicAdd(out0, -tt / (float)(BB * NP));
  }
}

// ---------------- tiled f32 conv1x1 GEMM (projector head, N=32 tiny)
template<int BM, int BN, int BK, int TM, int TN, bool BNRELU>
__global__ __launch_bounds__(256) void gemm_conv(
    const float* __restrict__ W, const float* __restrict__ bias,
    const float* __restrict__ X, float* __restrict__ Y,
    const float* __restrict__ bnscale, const float* __restrict__ bnshift,
    int M, int K, int N) {
  __shared__ float As[BK][BM + 4];
  __shared__ float Xs[BK][BN + 4];
  const int b = blockIdx.z;
  const int m0 = blockIdx.y * BM;
  const int n0 = blockIdx.x * BN;
  const int tid = threadIdx.x;
  const int tx = tid % (BN / TN);
  const int ty = tid / (BN / TN);
  const float* Xb = X + (size_t)b * K * N;
  float acc[TM][TN];
#pragma unroll
  for (int i = 0; i < TM; i++)
#pragma unroll
    for (int j = 0; j < TN; j++) acc[i][j] = 0.f;

  for (int k0 = 0; k0 < K; k0 += BK) {
    for (int i = tid; i < BM * BK; i += 256) {
      int r = i / BK, c = i % BK;
      As[c][r] = W[(size_t)(m0 + r) * K + k0 + c];
    }
    for (int i = tid; i < BK * BN; i += 256) {
      int r = i / BN, c = i % BN;
      float x = Xb[(size_t)(k0 + r) * N + n0 + c];
      if (BNRELU) x = fmaxf(fmaf(x, bnscale[k0 + r], bnshift[k0 + r]), 0.f);
      Xs[r][c] = x;
    }
    __syncthreads();
#pragma unroll 4
    for (int kk = 0; kk < BK; kk++) {
      float ra[TM], rb[TN];
#pragma unroll
      for (int i = 0; i < TM; i++) ra[i] = As[kk][ty * TM + i];
#pragma unroll
      for (int j = 0; j < TN; j++) rb[j] = Xs[kk][tx * TN + j];
#pragma unroll
      for (int i = 0; i < TM; i++)
#pragma unroll
        for (int j = 0; j < TN; j++) acc[i][j] = fmaf(ra[i], rb[j], acc[i][j]);
    }
    __syncthreads();
  }
#pragma unroll
  for (int i = 0; i < TM; i++) {
    float bm = bias[m0 + ty * TM + i];
#pragma unroll
    for (int j = 0; j < TN; j++)
      Y[((size_t)b * M + m0 + ty * TM + i) * N + n0 + tx * TN + j] = acc[i][j] + bm;
  }
}

// ---------------- tiny MLP gemm
template<bool BNRELU>
__global__ __launch_bounds__(256) void mlp_gemm(
    const float* __restrict__ W, const float* __restrict__ bias,
    const float* __restrict__ in, float* __restrict__ out,
    const float* __restrict__ sc, const float* __restrict__ sh, int M, int K) {
  int idx = blockIdx.x * 256 + threadIdx.x;
  if (idx >= BB * M) return;
  int s = idx / M, jj = idx % M;
  const float4* ip = (const float4*)(in + (size_t)s * K);
  const float4* wp = (const float4*)(W + (size_t)jj * K);
  float acc = 0.f;
  for (int c4 = 0; c4 < K / 4; c4++) {
    float4 x = ip[c4];
    float4 w = wp[c4];
    if (BNRELU) {
      int cb = c4 * 4;
      x.x = fmaxf(fmaf(x.x, sc[cb + 0], sh[cb + 0]), 0.f);
      x.y = fmaxf(fmaf(x.y, sc[cb + 1], sh[cb + 1]), 0.f);
      x.z = fmaxf(fmaf(x.z, sc[cb + 2], sh[cb + 2]), 0.f);
      x.w = fmaxf(fmaf(x.w, sc[cb + 3], sh[cb + 3]), 0.f);
    }
    acc += x.x * w.x + x.y * w.y + x.z * w.z + x.w * w.w;
  }
  out[idx] = acc + bias[jj];
}

__global__ __launch_bounds__(256) void mlp_bnstats(
    const float* __restrict__ mat, const float* __restrict__ g, const float* __restrict__ beta,
    float* __restrict__ scale, float* __restrict__ shift, int M) {
  int j = blockIdx.x * 256 + threadIdx.x;
  if (j >= M) return;
  float s = 0.f, sq = 0.f;
  for (int si = 0; si < BB; si++) { float v = mat[si * M + j]; s += v; sq += v * v; }
  float mean = s / (float)BB;
  float var = sq / (float)BB - mean * mean;
  float sc = g[j] / sqrtf(var + BN_EPS);
  scale[j] = sc; shift[j] = beta[j] - mean * sc;
}

// ---------------- launch ----------------
extern "C" void kernel_launch(void* const* d_in, const int* in_sizes, int n_in,
                              void* d_out, int out_size, void* d_ws, size_t ws_size,
                              hipStream_t stream) {
  const float* feat = (const float*)d_in[0];
  const float* cw1 = (const float*)d_in[1];  const float* cb1 = (const float*)d_in[2];
  const float* cg1 = (const float*)d_in[3];  const float* ct1 = (const float*)d_in[4];
  const float* cw2 = (const float*)d_in[5];  const float* cb2 = (const float*)d_in[6];
  const float* cg2 = (const float*)d_in[7];  const float* ct2 = (const float*)d_in[8];
  const float* cw3 = (const float*)d_in[9];  const float* cb3 = (const float*)d_in[10];
  const float* pw1 = (const float*)d_in[11]; const float* pb1 = (const float*)d_in[12];
  const float* pg1 = (const float*)d_in[13]; const float* pt1 = (const float*)d_in[14];
  const float* pw2 = (const float*)d_in[15]; const float* pb2 = (const float*)d_in[16];
  const float* pg2 = (const float*)d_in[17]; const float* pt2 = (const float*)d_in[18];
  const float* pw3 = (const float*)d_in[19]; const float* pb3 = (const float*)d_in[20];
  const float* mw1 = (const float*)d_in[21]; const float* mb1 = (const float*)d_in[22];
  const float* mg1 = (const float*)d_in[23]; const float* mt1 = (const float*)d_in[24];
  const float* mw2 = (const float*)d_in[25]; const float* mb2 = (const float*)d_in[26];
  const float* mg2 = (const float*)d_in[27]; const float* mt2 = (const float*)d_in[28];
  const float* mw3 = (const float*)d_in[29]; const float* mb3 = (const float*)d_in[30];
  float* out = (float*)d_out;

  // ---- workspace layout: total < 143 MiB proven bound; post-GEMM2 buffers alias Y1 ----
  char* p = (char*)d_ws;
  size_t off = 0;
  auto alloc = [&](size_t bytes) { char* r = p + off; off = (off + bytes + 255) & ~(size_t)255; return r; };
  float* Y1 = (float*)alloc(67108864);   // [8][512][4096] f32
  float* Y2 = (float*)alloc(67108864);
  u16* W1H = (u16*)alloc(1048576); u16* W1M = (u16*)alloc(1048576); u16* W1L = (u16*)alloc(1048576);
  u16* W2H = (u16*)alloc(524288);  u16* W2M = (u16*)alloc(524288);  u16* W2L = (u16*)alloc(524288);
  u16* W3H = (u16*)alloc(32768);   u16* W3M = (u16*)alloc(32768);   u16* W3L = (u16*)alloc(32768);
  float* SC1  = (float*)alloc(2048); float* SH1 = (float*)alloc(2048);
  float* SC2  = (float*)alloc(2048); float* SH2 = (float*)alloc(2048);
  float* PSC1 = (float*)alloc(2048); float* PSH1 = (float*)alloc(2048);
  float* PSC2 = (float*)alloc(2048); float* PSH2 = (float*)alloc(2048);
  float* MSC1 = (float*)alloc(2048); float* MSH1 = (float*)alloc(2048);
  float* MSC2 = (float*)alloc(2048); float* MSH2 = (float*)alloc(2048);
  // ---- sub-arena inside Y1's region: first written AFTER GEMM2 completes ----
  char* q = (char*)Y1;
  size_t qoff = 0;
  auto qalloc = [&](size_t bytes) { char* r = q + qoff; qoff = (qoff + bytes + 255) & ~(size_t)255; return r; };
  float* LSC  = (float*)qalloc(4194304);  // [8][32][4096], written by GEMM3
  float* SCRB = (float*)qalloc(4194304);  // score
  float* LSE  = (float*)qalloc(131072);
  float* NFN  = (float*)qalloc(131072);
  float* NMUN = (float*)qalloc(1024);
  float* GBUF = (float*)qalloc(819200);   // 25*8*16*32*2 floats
  float* GMAX = (float*)qalloc(32768);
  float* MH1  = (float*)qalloc(16384);
  float* MH2  = (float*)qalloc(16384);
  float* T1   = (float*)qalloc(524288);
  float* T2   = (float*)qalloc(524288);
  // contiguous memset region: PIRAW | VLAD | COSTD (memset AFTER GEMM2 in stream)
  char* MS = qalloc(1024 + 1048576 + 4194304);
  float* PIRAW = (float*)MS;
  float* VLAD  = (float*)(MS + 1024);
  float* COSTD = (float*)(MS + 1024 + 1048576);

  hipMemsetAsync(d_out, 0, sizeof(float), stream);

  float logp = logf(1.0f / NP + 1e-8f);
  float logq = logf(1.0f / KC + 1e-8f);
  dim3 blk(256);

  // weight permute + 3-split
  convW3<128><<<dim3(4, 32), blk, 0, stream>>>(cw1, W1H, W1M, W1L, 1024);
  convW3<128><<<dim3(4, 16), blk, 0, stream>>>(cw2, W2H, W2M, W2L, 512);
  convW3<32><<<dim3(1, 16), blk, 0, stream>>>(cw3, W3H, W3M, W3L, 512);

  // score head: bf16x3 MFMA (f32-equivalent)
  gemm_mfma3<128, 4, 4, 4, 2, false><<<dim3(128, 1, 8), blk, 0, stream>>>(
      W1H, W1M, W1L, cb1, feat, nullptr, nullptr, Y1, 1024, 512);
  bnstats<<<dim3(512), blk, 0, stream>>>(Y1, cg1, ct1, SC1, SH1, 512, NP);
  gemm_mfma3<128, 4, 4, 4, 2, true><<<dim3(128, 1, 8), blk, 0, stream>>>(
      W2H, W2M, W2L, cb2, Y1, SC1, SH1, Y2, 512, 512);
  bnstats<<<dim3(512), blk, 0, stream>>>(Y2, cg2, ct2, SC2, SH2, 512, NP);
  // Y1 is now dead -> zero the aliased accumulation buffers inside it
  hipMemsetAsync(MS, 0, 1024 + 1048576 + 4194304, stream);
  gemm_mfma3<32, 1, 2, 2, 1, true><<<dim3(32, 1, 8), blk, 0, stream>>>(
      W3H, W3M, W3L, cb3, Y2, SC2, SH2, LSC, 512, 32);

  // softmax + pi + lse
  softmax_pi<<<dim3(BB * NP / 256), blk, 0, stream>>>(LSC, SCRB, LSE, PIRAW);

  // vlad
  vlad_accum<<<dim3(8, DD / 128, BB), blk, 0, stream>>>(feat, SCRB, VLAD);
  vlad_fin<<<dim3(BB * DD / 256), blk, 0, stream>>>(VLAD, PIRAW, GMAX);
  nmu_norm_k<<<dim3(BB), blk, 0, stream>>>(VLAD, NMUN);
  nf_norm_k<<<dim3(BB * NP / 256), blk, 0, stream>>>(feat, NFN);

  // cost
  cost_accum<<<dim3(4, NP / 128, BB), blk, 0, stream>>>(feat, VLAD, COSTD);
  cost_fin<<<dim3(BB * NP * KC / 256), blk, 0, stream>>>(COSTD, NFN, NMUN);

  // sinkhorn: 25 iterations, 128 blocks each (grid barrier = launch boundary)
  for (int t = 1; t <= 25; t++)
    sinkhorn_iter<<<dim3(BB * NJB), blk, 0, stream>>>(COSTD, GBUF, t, logp, logq);
  loss_kernel<<<dim3(BB * NJB), blk, 0, stream>>>(COSTD, GBUF, LSC, LSE, out, logp, logq);

  // predictor MLP on max-pooled vlad
  mlp_gemm<false><<<dim3(BB * HH / 256), blk, 0, stream>>>(mw1, mb1, GMAX, MH1, nullptr, nullptr, HH, DD);
  mlp_bnstats<<<dim3(2), blk, 0, stream>>>(MH1, mg1, mt1, MSC1, MSH1, HH);
  mlp_gemm<true><<<dim3(BB * HH / 256), blk, 0, stream>>>(mw2, mb2, MH1, MH2, MSC1, MSH1, HH, HH);
  mlp_bnstats<<<dim3(2), blk, 0, stream>>>(MH2, mg2, mt2, MSC2, MSH2, HH);
  mlp_gemm<true><<<dim3(BB * PP / 256), blk, 0, stream>>>(mw3, mb3, MH2, out + 1 + BB * PP * KC, MSC2, MSH2, PP, HH);

  // projector conv head on vlad (N=32, f32)
  gemm_conv<64, 32, 16, 4, 2, false><<<dim3(1, HH / 64, BB), blk, 0, stream>>>(pw1, pb1, VLAD, T1, nullptr, nullptr, HH, DD, KC);
  bnstats<<<dim3(512), blk, 0, stream>>>(T1, pg1, pt1, PSC1, PSH1, HH, KC);
  gemm_conv<64, 32, 16, 4, 2, true><<<dim3(1, HH / 64, BB), blk, 0, stream>>>(pw2, pb2, T1, T2, PSC1, PSH1, HH, HH, KC);
  bnstats<<<dim3(512), blk, 0, stream>>>(T2, pg2, pt2, PSC2, PSH2, HH, KC);
  gemm_conv<64, 32, 16, 4, 2, true><<<dim3(1, PP / 64, BB), blk, 0, stream>>>(pw3, pb3, T2, out + 1, PSC2, PSH2, PP, HH, KC);
}